// Round 4
// baseline (993.163 us; speedup 1.0000x reference)
//
#include <hip/hip_runtime.h>
#include <hip/hip_bf16.h>

// Problem constants
#define TT   128
#define BB   256
#define MM   512
#define GG   2560
#define K1P  960   // 940 padded to 960 (30 * 32)

typedef __attribute__((ext_vector_type(8))) short bf16x8;
typedef __attribute__((ext_vector_type(4))) short bf16x4;
typedef __attribute__((ext_vector_type(4))) float f32x4;
typedef __attribute__((ext_vector_type(4))) unsigned u32x4;

__device__ __forceinline__ float bf2f(unsigned short u){
  union { unsigned u; float f; } v; v.u = ((unsigned)u) << 16; return v.f;
}
__device__ __forceinline__ unsigned short f2bf(float f){
  union { float f; unsigned u; } v; v.f = f;
  unsigned r = v.u + 0x7fffu + ((v.u >> 16) & 1u);
  return (unsigned short)(r >> 16);
}
__device__ __forceinline__ float sigmoidf_(float x){ return 1.f/(1.f + __expf(-x)); }
__device__ __forceinline__ float tanhf_(float x){
  x = fminf(15.f, fmaxf(-15.f, x));
  float e = __expf(2.f*x);
  return (e - 1.f)/(e + 1.f);
}

// MALL-coherent (cross-XCD) 16B load / 4B store: sc0 sc1 bypass L1/L2,
// coherence point = Infinity Cache. No cache-maintenance fences needed.
__device__ __forceinline__ u32x4 load_coh16(const void* p){
  u32x4 r;
  asm volatile("global_load_dwordx4 %0, %1, off sc0 sc1" : "=v"(r) : "v"(p) : "memory");
  return r;
}
__device__ __forceinline__ void store_coh4(void* p, unsigned v){
  asm volatile("global_store_dword %0, %1, off sc0 sc1" :: "v"(p), "v"(v) : "memory");
}

// async global->LDS, 16B per lane; LDS dest = wave-uniform base + lane*16
__device__ __forceinline__ void gll16(const unsigned short* g, unsigned short* l){
  __builtin_amdgcn_global_load_lds(
      (const __attribute__((address_space(1))) void*)(g),
      (__attribute__((address_space(3))) void*)(l),
      16, 0, 0);
}

// ---------------- staging kernels ----------------

__global__ __launch_bounds__(256) void stage_a(const float* __restrict__ word,
                                               const float* __restrict__ tag,
                                               const float* __restrict__ rel,
                                               const float* __restrict__ kin,
                                               unsigned short* __restrict__ A){
  long id = (long)blockIdx.x * 256 + threadIdx.x;     // chunk over 32768*120
  int row = (int)(id / 120);
  int c8  = (int)(id % 120) * 8;
  bf16x8 o;
  #pragma unroll
  for (int j = 0; j < 8; ++j){
    int col = c8 + j; float v;
    if      (col < 300) v = word[(long)row*300 + col];
    else if (col < 364) v = tag [(long)row*64  + col-300];
    else if (col < 428) v = rel [(long)row*64  + col-364];
    else if (col < 940) v = kin [(long)row*512 + col-428];
    else v = 0.f;
    o[j] = (short)f2bf(v);
  }
  *reinterpret_cast<bf16x8*>(A + (long)row*K1P + c8) = o;
}

__global__ __launch_bounds__(256) void stage_wt(const float* __restrict__ Ww,
                                                const float* __restrict__ Wt,
                                                const float* __restrict__ Wr,
                                                const float* __restrict__ Wk,
                                                unsigned short* __restrict__ WT){
  long id = (long)blockIdx.x * 256 + threadIdx.x;   // 2560*960
  int kk = (int)(id % K1P);
  int n  = (int)(id / K1P);
  float v;
  if      (kk < 300) v = Ww[(long)kk*GG + n];
  else if (kk < 364) v = Wt[(long)(kk-300)*GG + n];
  else if (kk < 428) v = Wr[(long)(kk-364)*GG + n];
  else if (kk < 940) v = Wk[(long)(kk-428)*GG + n];
  else v = 0.f;
  WT[(long)n*K1P + kk] = f2bf(v);
}

__global__ __launch_bounds__(256) void stage_wht(const float* __restrict__ Wh,
                                                 unsigned short* __restrict__ WhT){
  long id = (long)blockIdx.x * 256 + threadIdx.x;   // 2560*512
  int kk = (int)(id % MM);
  int n  = (int)(id / MM);
  WhT[(long)n*MM + kk] = f2bf(Wh[(long)kk*GG + n]);
}

__global__ __launch_bounds__(256) void init_h(const float* __restrict__ h0,
                                              unsigned short* __restrict__ hb){
  int id = blockIdx.x * 256 + threadIdx.x;          // 131072
  hb[id] = f2bf(h0[id]);
}

// ---------------- xp GEMM: m97 structure ----------------
// 128x128 tile, BK=32, single-buffered LINEAR LDS (required by global_load_lds),
// 2 barriers per K-step, 4x global_load_lds_dwordx4 per thread per K-step.
// Staging geometry: instr (wave, s), s in {0,1}: LDS byte base=(wave*2+s)*1024;
// lane l covers bytes [base+l*16, +16) -> row=(wave*2+s)*16 + l/4, kelem=(l&3)*8.
__global__ __launch_bounds__(256) void gemm_xp(const unsigned short* __restrict__ A,
                                               const unsigned short* __restrict__ WT,
                                               const float* __restrict__ bias,
                                               unsigned short* __restrict__ XP){
  __shared__ unsigned short As[128*32];   // 8 KB, linear [row][k]
  __shared__ unsigned short Bs[128*32];   // 8 KB, linear [ncol][k]
  const int tid  = threadIdx.x;
  const int wave = tid >> 6, lane = tid & 63;
  const int wr   = wave >> 1, wc = wave & 1;
  const int lrow = lane & 15, lhi = lane >> 4;
  const long row0 = (long)blockIdx.x * 128;
  const long col0 = (long)blockIdx.y * 128;

  // per-lane global base addresses (k-offset added per K-step)
  const int sr0 = (wave*2 + 0)*16 + (lane >> 2);
  const int sr1 = (wave*2 + 1)*16 + (lane >> 2);
  const int sk  = (lane & 3) * 8;
  const unsigned short* ga0 = A  + (row0 + sr0)*K1P + sk;
  const unsigned short* ga1 = A  + (row0 + sr1)*K1P + sk;
  const unsigned short* gb0 = WT + (col0 + sr0)*K1P + sk;
  const unsigned short* gb1 = WT + (col0 + sr1)*K1P + sk;
  // wave-uniform LDS bases (elements)
  unsigned short* lA0 = As + (wave*2 + 0)*512;
  unsigned short* lA1 = As + (wave*2 + 1)*512;
  unsigned short* lB0 = Bs + (wave*2 + 0)*512;
  unsigned short* lB1 = Bs + (wave*2 + 1)*512;

  f32x4 acc[4][4] = {};
  for (int ks = 0; ks < 30; ++ks){
    const int k0 = ks * 32;
    __syncthreads();                    // prev iter's LDS reads done
    gll16(ga0 + k0, lA0);
    gll16(ga1 + k0, lA1);
    gll16(gb0 + k0, lB0);
    gll16(gb1 + k0, lB1);
    __syncthreads();                    // vmcnt(0) drain -> tiles ready
    bf16x8 af[4], bfr[4];
    #pragma unroll
    for (int mi = 0; mi < 4; ++mi)
      af[mi] = *reinterpret_cast<const bf16x8*>(As + (wr*64 + mi*16 + lrow)*32 + lhi*8);
    #pragma unroll
    for (int ni = 0; ni < 4; ++ni)
      bfr[ni] = *reinterpret_cast<const bf16x8*>(Bs + (wc*64 + ni*16 + lrow)*32 + lhi*8);
    #pragma unroll
    for (int mi = 0; mi < 4; ++mi)
      #pragma unroll
      for (int ni = 0; ni < 4; ++ni)
        acc[mi][ni] = __builtin_amdgcn_mfma_f32_16x16x32_bf16(af[mi], bfr[ni], acc[mi][ni], 0, 0, 0);
  }
  // epilogue (unchanged, verified): + bias, XP stored [T][G][B]
  const int t     = (int)(row0 >> 8);
  const int brow0 = (int)(row0 & 255);
  #pragma unroll
  for (int ni = 0; ni < 4; ++ni){
    const int col = (int)col0 + wc*64 + ni*16 + lrow;
    const float bv = bias[col];
    #pragma unroll
    for (int mi = 0; mi < 4; ++mi){
      const int b4 = brow0 + wr*64 + mi*16 + lhi*4;
      bf16x4 pk;
      #pragma unroll
      for (int j = 0; j < 4; ++j) pk[j] = (short)f2bf(acc[mi][ni][j] + bv);
      *reinterpret_cast<bf16x4*>(XP + ((long)t*GG + col)*BB + b4) = pk;
    }
  }
}

// ---------------- fused persistent recurrence ----------------
// grid 256 blocks x 256 threads. Block = (bt in 0..7) x (mc in 0..31):
// owns batch rows [bt*32, bt*32+32) and m-cols [mc*16, mc*16+16), all 5 gates.
// Wh B-fragments register-resident; c in registers.
// h ping-pong via MALL-coherent sc0sc1; per-bt 32-block barrier, relaxed agent
// atomics, ALL threads poll (no post-poll __syncthreads). 3 syncs per step.
__global__ __launch_bounds__(256, 1) void lstm_fused(const unsigned short* __restrict__ XP,
                                                     const float* __restrict__ q,
                                                     const unsigned short* __restrict__ WhT,
                                                     const float* __restrict__ c0,
                                                     unsigned short* __restrict__ hb0,
                                                     unsigned short* __restrict__ hb1,
                                                     float* __restrict__ out,
                                                     unsigned* __restrict__ cnts){
  constexpr int HSTR = 520;
  __shared__ unsigned short Hs[32*HSTR];         // 33,280 B
  __shared__ float Ga[2][5][16][17];             // 10,880 B
  const int tid  = threadIdx.x;
  const int wave = tid >> 6, lane = tid & 63;
  const int lrow = lane & 15, lhi = lane >> 4;
  const int rt = wave >> 1;                      // row-tile 0/1 (16 rows each)
  const int gs = wave & 1;                       // gate-set: 0 -> {0,1,2}, 1 -> {3,4}
  const int gbase = gs ? 3 : 0;
  const int bt = blockIdx.x >> 5, mc = blockIdx.x & 31;
  const int b0 = bt * 32, m0 = mc * 16;
  unsigned* cnt = cnts + bt * 64;                // per-bt counter, own cacheline

  // persistent Wh B-fragments (static indexing only)
  bf16x8 Breg[3][16];
  #pragma unroll
  for (int kf = 0; kf < 16; ++kf){
    Breg[0][kf] = *reinterpret_cast<const bf16x8*>(WhT + (long)((gbase+0)*MM + m0 + lrow)*MM + kf*32 + lhi*8);
    Breg[1][kf] = *reinterpret_cast<const bf16x8*>(WhT + (long)((gbase+1)*MM + m0 + lrow)*MM + kf*32 + lhi*8);
  }
  if (gs == 0){
    #pragma unroll
    for (int kf = 0; kf < 16; ++kf)
      Breg[2][kf] = *reinterpret_cast<const bf16x8*>(WhT + (long)(2*MM + m0 + lrow)*MM + kf*32 + lhi*8);
  }

  // update-phase mapping: 2 states per thread
  const int bl = tid >> 3, mi2 = (tid & 7) * 2;
  const int rt2 = bl >> 4, brow = bl & 15;
  const int gb = b0 + bl, gm = m0 + mi2;
  float cx = c0[(long)gb*MM + gm];
  float cy = c0[(long)gb*MM + gm + 1];

  // prefetch t=0 xp/q
  unsigned short xv[5][2]; float qx, qy;
  #pragma unroll
  for (int j = 0; j < 5; ++j){
    xv[j][0] = XP[((long)0*GG + j*MM + gm    )*BB + gb];
    xv[j][1] = XP[((long)0*GG + j*MM + gm + 1)*BB + gb];
  }
  qx = q[((long)0*BB + gb)*MM + gm];
  qy = q[((long)0*BB + gb)*MM + gm + 1];

  for (int t = 0; t < TT; ++t){
    const unsigned short* hc = (t & 1) ? hb1 : hb0;
    unsigned short*       hn = (t & 1) ? hb0 : hb1;

    // stage h tile (32 x 512) into LDS via MALL-coherent loads
    u32x4 hreg[8];
    #pragma unroll
    for (int p = 0; p < 8; ++p){
      int idx = p*2048 + tid*8;
      int row = idx >> 9, col = idx & 511;
      hreg[p] = load_coh16(hc + (long)(b0 + row)*MM + col);
    }
    asm volatile("s_waitcnt vmcnt(0)" ::: "memory");
    __builtin_amdgcn_sched_barrier(0);
    #pragma unroll
    for (int p = 0; p < 8; ++p){
      int idx = p*2048 + tid*8;
      int row = idx >> 9, col = idx & 511;
      *reinterpret_cast<u32x4*>(Hs + row*HSTR + col) = hreg[p];
    }
    __syncthreads();                               // sync1: Hs ready

    // h @ Wh for this wave's (rt, gate-set)
    f32x4 acc0 = {}, acc1 = {}, acc2 = {};
    #pragma unroll
    for (int kf = 0; kf < 16; ++kf){
      bf16x8 af = *reinterpret_cast<const bf16x8*>(Hs + (rt*16 + lrow)*HSTR + kf*32 + lhi*8);
      acc0 = __builtin_amdgcn_mfma_f32_16x16x32_bf16(af, Breg[0][kf], acc0, 0, 0, 0);
      acc1 = __builtin_amdgcn_mfma_f32_16x16x32_bf16(af, Breg[1][kf], acc1, 0, 0, 0);
      if (gs == 0)
        acc2 = __builtin_amdgcn_mfma_f32_16x16x32_bf16(af, Breg[2][kf], acc2, 0, 0, 0);
    }

    // exchange partial gates via LDS (D: row=b=(lhi*4+j), col=m=lrow)
    #pragma unroll
    for (int j = 0; j < 4; ++j){
      Ga[rt][gbase+0][lhi*4 + j][lrow] = acc0[j];
      Ga[rt][gbase+1][lhi*4 + j][lrow] = acc1[j];
      if (gs == 0) Ga[rt][2][lhi*4 + j][lrow] = acc2[j];
    }
    __syncthreads();                               // sync2: Ga ready

    // gates for this thread's 2 states
    float gv[5][2];
    #pragma unroll
    for (int j = 0; j < 5; ++j){
      gv[j][0] = Ga[rt2][j][brow][mi2    ] + bf2f(xv[j][0]);
      gv[j][1] = Ga[rt2][j][brow][mi2 + 1] + bf2f(xv[j][1]);
    }
    const float qx_t = qx, qy_t = qy;

    // prefetch next step's xp/q (independent of barrier; hides under VALU+wait)
    if (t < TT - 1){
      #pragma unroll
      for (int j = 0; j < 5; ++j){
        xv[j][0] = XP[((long)(t+1)*GG + j*MM + gm    )*BB + gb];
        xv[j][1] = XP[((long)(t+1)*GG + j*MM + gm + 1)*BB + gb];
      }
      qx = q[((long)(t+1)*BB + gb)*MM + gm];
      qy = q[((long)(t+1)*BB + gb)*MM + gm + 1];
    }

    float hx, hy;
    {
      const float i_ = sigmoidf_(gv[0][0]);
      const float fd = sigmoidf_(gv[1][0]);
      const float fl = sigmoidf_(gv[2][0]);
      const float o_ = sigmoidf_(gv[3][0]);
      const float u_ = tanhf_(gv[4][0]);
      const float cn = i_*u_ + fd*qx_t + fl*cx;
      cx = cn; hx = o_*tanhf_(cn);
    }
    {
      const float i_ = sigmoidf_(gv[0][1]);
      const float fd = sigmoidf_(gv[1][1]);
      const float fl = sigmoidf_(gv[2][1]);
      const float o_ = sigmoidf_(gv[3][1]);
      const float u_ = tanhf_(gv[4][1]);
      const float cn = i_*u_ + fd*qy_t + fl*cy;
      cy = cn; hy = o_*tanhf_(cn);
    }
    const unsigned hv = (unsigned)f2bf(hx) | ((unsigned)f2bf(hy) << 16);
    store_coh4(hn + (long)gb*MM + gm, hv);
    if (t == TT - 1){
      out[(long)gb*1024 + gm]           = hx;
      out[(long)gb*1024 + gm + 1]       = hy;
      out[(long)gb*1024 + 512 + gm]     = cx;
      out[(long)gb*1024 + 512 + gm + 1] = cy;
    }

    // per-bt barrier: sync3 drains every thread's h store (vmcnt(0) before
    // s_barrier) -> all 32 rows visible at MALL; then arrive + all-thread poll.
    if (t != TT - 1){
      __syncthreads();                             // sync3
      if (tid == 0)
        __hip_atomic_fetch_add(cnt, 1u, __ATOMIC_RELAXED, __HIP_MEMORY_SCOPE_AGENT);
      const unsigned target = (unsigned)(t + 1) * 32u;
      unsigned spins = 0;
      while (__hip_atomic_load(cnt, __ATOMIC_RELAXED, __HIP_MEMORY_SCOPE_AGENT) < target){
        __builtin_amdgcn_s_sleep(1);
        if (++spins > (1u << 20)) break;           // safety valve
      }
      asm volatile("" ::: "memory");
    }
  }
}

extern "C" void kernel_launch(void* const* d_in, const int* in_sizes, int n_in,
                              void* d_out, int out_size, void* d_ws, size_t ws_size,
                              hipStream_t stream){
  (void)in_sizes; (void)n_in; (void)out_size; (void)ws_size;
  const float* word = (const float*)d_in[0];
  const float* tag  = (const float*)d_in[1];
  const float* rel  = (const float*)d_in[2];
  const float* kin  = (const float*)d_in[3];
  const float* q    = (const float*)d_in[4];
  const float* h0   = (const float*)d_in[5];
  const float* c0   = (const float*)d_in[6];
  const float* Ww   = (const float*)d_in[7];
  const float* Wt   = (const float*)d_in[8];
  const float* Wr   = (const float*)d_in[9];
  const float* Wk   = (const float*)d_in[10];
  const float* Wh   = (const float*)d_in[11];
  const float* bias = (const float*)d_in[12];
  float* out = (float*)d_out;

  char* ws = (char*)d_ws;
  size_t off = 0;
  auto alloc = [&](size_t bytes)->void*{
    void* p = ws + off; off = (off + bytes + 255) & ~(size_t)255; return p;
  };
  unsigned short* Abf = (unsigned short*)alloc((size_t)TT*BB*K1P*2);   // 62.9 MB
  unsigned short* WT  = (unsigned short*)alloc((size_t)GG*K1P*2);      // 4.9 MB
  unsigned short* WhT = (unsigned short*)alloc((size_t)GG*MM*2);       // 2.6 MB
  unsigned short* XP  = (unsigned short*)alloc((size_t)TT*BB*GG*2);    // 167.8 MB
  unsigned short* hb0 = (unsigned short*)alloc((size_t)BB*MM*2);
  unsigned short* hb1 = (unsigned short*)alloc((size_t)BB*MM*2);
  unsigned*       cnt = (unsigned*)alloc(8 * 64 * sizeof(unsigned));   // per-bt counters

  hipMemsetAsync(cnt, 0, 8 * 64 * sizeof(unsigned), stream);

  stage_a  <<<dim3((TT*BB*(K1P/8) + 255)/256), 256, 0, stream>>>(word, tag, rel, kin, Abf);
  stage_wt <<<dim3((GG*K1P + 255)/256),        256, 0, stream>>>(Ww, Wt, Wr, Wk, WT);
  stage_wht<<<dim3((GG*MM + 255)/256),         256, 0, stream>>>(Wh, WhT);
  init_h   <<<dim3((BB*MM + 255)/256),         256, 0, stream>>>(h0, hb0);

  gemm_xp<<<dim3(TT*BB/128, GG/128), 256, 0, stream>>>(Abf, WT, bias, XP);

  lstm_fused<<<dim3(256), 256, 0, stream>>>(XP, q, WhT, c0, hb0, hb1, out, cnt);
}

// Round 5
// 849.625 us; speedup vs baseline: 1.1689x; 1.1689x over previous
//
#include <hip/hip_runtime.h>
#include <hip/hip_bf16.h>

// Problem constants
#define TT   128
#define BB   256
#define MM   512
#define GG   2560
#define K1P  960   // 940 padded to 960 (30 * 32)

typedef __attribute__((ext_vector_type(8))) short bf16x8;
typedef __attribute__((ext_vector_type(4))) short bf16x4;
typedef __attribute__((ext_vector_type(4))) float f32x4;
typedef __attribute__((ext_vector_type(4))) unsigned u32x4;

__device__ __forceinline__ float bf2f(unsigned short u){
  union { unsigned u; float f; } v; v.u = ((unsigned)u) << 16; return v.f;
}
__device__ __forceinline__ unsigned short f2bf(float f){
  union { float f; unsigned u; } v; v.f = f;
  unsigned r = v.u + 0x7fffu + ((v.u >> 16) & 1u);
  return (unsigned short)(r >> 16);
}
__device__ __forceinline__ float sigmoidf_(float x){ return 1.f/(1.f + __expf(-x)); }
__device__ __forceinline__ float tanhf_(float x){
  x = fminf(15.f, fmaxf(-15.f, x));
  float e = __expf(2.f*x);
  return (e - 1.f)/(e + 1.f);
}

// MALL-coherent (cross-XCD) accesses: sc0 sc1 bypass L1/L2; coherence point =
// Infinity Cache. No cache-maintenance fences needed.
__device__ __forceinline__ bf16x8 load_coh16b(const void* p){
  bf16x8 r;
  asm volatile("global_load_dwordx4 %0, %1, off sc0 sc1" : "=v"(r) : "v"(p) : "memory");
  return r;
}
__device__ __forceinline__ void store_coh4(void* p, unsigned v){
  asm volatile("global_store_dword %0, %1, off sc0 sc1" :: "v"(p), "v"(v) : "memory");
}

// async global->LDS, 16B per lane; LDS dest = wave-uniform base + lane*16
__device__ __forceinline__ void gll16(const unsigned short* g, unsigned short* l){
  __builtin_amdgcn_global_load_lds(
      (const __attribute__((address_space(1))) void*)(g),
      (__attribute__((address_space(3))) void*)(l),
      16, 0, 0);
}

// ---------------- staging kernels ----------------

__global__ __launch_bounds__(256) void stage_a(const float* __restrict__ word,
                                               const float* __restrict__ tag,
                                               const float* __restrict__ rel,
                                               const float* __restrict__ kin,
                                               unsigned short* __restrict__ A){
  long id = (long)blockIdx.x * 256 + threadIdx.x;     // chunk over 32768*120
  int row = (int)(id / 120);
  int c8  = (int)(id % 120) * 8;
  bf16x8 o;
  #pragma unroll
  for (int j = 0; j < 8; ++j){
    int col = c8 + j; float v;
    if      (col < 300) v = word[(long)row*300 + col];
    else if (col < 364) v = tag [(long)row*64  + col-300];
    else if (col < 428) v = rel [(long)row*64  + col-364];
    else if (col < 940) v = kin [(long)row*512 + col-428];
    else v = 0.f;
    o[j] = (short)f2bf(v);
  }
  *reinterpret_cast<bf16x8*>(A + (long)row*K1P + c8) = o;
}

__global__ __launch_bounds__(256) void stage_wt(const float* __restrict__ Ww,
                                                const float* __restrict__ Wt,
                                                const float* __restrict__ Wr,
                                                const float* __restrict__ Wk,
                                                unsigned short* __restrict__ WT){
  long id = (long)blockIdx.x * 256 + threadIdx.x;   // 2560*960
  int kk = (int)(id % K1P);
  int n  = (int)(id / K1P);
  float v;
  if      (kk < 300) v = Ww[(long)kk*GG + n];
  else if (kk < 364) v = Wt[(long)(kk-300)*GG + n];
  else if (kk < 428) v = Wr[(long)(kk-364)*GG + n];
  else if (kk < 940) v = Wk[(long)(kk-428)*GG + n];
  else v = 0.f;
  WT[(long)n*K1P + kk] = f2bf(v);
}

__global__ __launch_bounds__(256) void stage_wht(const float* __restrict__ Wh,
                                                 unsigned short* __restrict__ WhT){
  long id = (long)blockIdx.x * 256 + threadIdx.x;   // 2560*512
  int kk = (int)(id % MM);
  int n  = (int)(id / MM);
  WhT[(long)n*MM + kk] = f2bf(Wh[(long)kk*GG + n]);
}

__global__ __launch_bounds__(256) void init_h(const float* __restrict__ h0,
                                              unsigned short* __restrict__ hb){
  int id = blockIdx.x * 256 + threadIdx.x;          // 131072
  hb[id] = f2bf(h0[id]);
}

// ---------------- xp GEMM: m97 structure (unchanged from R4) ----------------
__global__ __launch_bounds__(256) void gemm_xp(const unsigned short* __restrict__ A,
                                               const unsigned short* __restrict__ WT,
                                               const float* __restrict__ bias,
                                               unsigned short* __restrict__ XP){
  __shared__ unsigned short As[128*32];   // 8 KB, linear [row][k]
  __shared__ unsigned short Bs[128*32];   // 8 KB, linear [ncol][k]
  const int tid  = threadIdx.x;
  const int wave = tid >> 6, lane = tid & 63;
  const int wr   = wave >> 1, wc = wave & 1;
  const int lrow = lane & 15, lhi = lane >> 4;
  const long row0 = (long)blockIdx.x * 128;
  const long col0 = (long)blockIdx.y * 128;

  const int sr0 = (wave*2 + 0)*16 + (lane >> 2);
  const int sr1 = (wave*2 + 1)*16 + (lane >> 2);
  const int sk  = (lane & 3) * 8;
  const unsigned short* ga0 = A  + (row0 + sr0)*K1P + sk;
  const unsigned short* ga1 = A  + (row0 + sr1)*K1P + sk;
  const unsigned short* gb0 = WT + (col0 + sr0)*K1P + sk;
  const unsigned short* gb1 = WT + (col0 + sr1)*K1P + sk;
  unsigned short* lA0 = As + (wave*2 + 0)*512;
  unsigned short* lA1 = As + (wave*2 + 1)*512;
  unsigned short* lB0 = Bs + (wave*2 + 0)*512;
  unsigned short* lB1 = Bs + (wave*2 + 1)*512;

  f32x4 acc[4][4] = {};
  for (int ks = 0; ks < 30; ++ks){
    const int k0 = ks * 32;
    __syncthreads();
    gll16(ga0 + k0, lA0);
    gll16(ga1 + k0, lA1);
    gll16(gb0 + k0, lB0);
    gll16(gb1 + k0, lB1);
    __syncthreads();
    bf16x8 af[4], bfr[4];
    #pragma unroll
    for (int mi = 0; mi < 4; ++mi)
      af[mi] = *reinterpret_cast<const bf16x8*>(As + (wr*64 + mi*16 + lrow)*32 + lhi*8);
    #pragma unroll
    for (int ni = 0; ni < 4; ++ni)
      bfr[ni] = *reinterpret_cast<const bf16x8*>(Bs + (wc*64 + ni*16 + lrow)*32 + lhi*8);
    #pragma unroll
    for (int mi = 0; mi < 4; ++mi)
      #pragma unroll
      for (int ni = 0; ni < 4; ++ni)
        acc[mi][ni] = __builtin_amdgcn_mfma_f32_16x16x32_bf16(af[mi], bfr[ni], acc[mi][ni], 0, 0, 0);
  }
  const int t     = (int)(row0 >> 8);
  const int brow0 = (int)(row0 & 255);
  #pragma unroll
  for (int ni = 0; ni < 4; ++ni){
    const int col = (int)col0 + wc*64 + ni*16 + lrow;
    const float bv = bias[col];
    #pragma unroll
    for (int mi = 0; mi < 4; ++mi){
      const int b4 = brow0 + wr*64 + mi*16 + lhi*4;
      bf16x4 pk;
      #pragma unroll
      for (int j = 0; j < 4; ++j) pk[j] = (short)f2bf(acc[mi][ni][j] + bv);
      *reinterpret_cast<bf16x4*>(XP + ((long)t*GG + col)*BB + b4) = pk;
    }
  }
}

// ---------------- fused persistent recurrence ----------------
// grid 256 x 256. Block = (bt 0..7) x (mc 0..31): batch rows [bt*32,+32),
// m-cols [mc*16,+16), all 5 gates. K-SPLIT waves: wave w owns k-quarter
// [w*128,(w+1)*128) for all 5 gates x both 16-row tiles.
//   Breg: 5 gates x 4 kf = 80 VGPR (actually register-resident, unlike R3/R4)
//   h fragments loaded straight to regs (sc0sc1), counted vmcnt waits
//   cross-wave k-reduction of gate partials via LDS Part
// Barrier: R3-proven tid0 poll + syncthreads broadcast. 3 syncs/step.
__global__ __launch_bounds__(256, 1) void lstm_fused(const unsigned short* __restrict__ XP,
                                                     const float* __restrict__ q,
                                                     const unsigned short* __restrict__ WhT,
                                                     const float* __restrict__ c0,
                                                     unsigned short* __restrict__ hb0,
                                                     unsigned short* __restrict__ hb1,
                                                     float* __restrict__ out,
                                                     unsigned* __restrict__ cnts){
  __shared__ float Part[4][5][2][16][20];        // [w][gate][rt][m][b pad20] 51.2 KB
  const int tid  = threadIdx.x;
  const int w    = tid >> 6, lane = tid & 63;
  const int lrow = lane & 15, lhi = lane >> 4;
  const int bt = blockIdx.x >> 5, mc = blockIdx.x & 31;
  const int b0 = bt * 32, m0 = mc * 16;
  unsigned* cnt = cnts + bt * 64;                // per-bt counter, own cacheline

  // this wave's k-quarter of Wh for all 5 gates (80 VGPR, loop fully unrolled)
  bf16x8 Breg[5][4];
  #pragma unroll
  for (int g = 0; g < 5; ++g)
    #pragma unroll
    for (int kf = 0; kf < 4; ++kf)
      Breg[g][kf] = *reinterpret_cast<const bf16x8*>(
          WhT + (long)(g*MM + m0 + lrow)*MM + w*128 + kf*32 + lhi*8);

  // update-phase mapping: 2 states per thread
  const int bl = tid >> 3, mi2 = (tid & 7) * 2;
  const int rt2 = bl >> 4, brow = bl & 15;
  const int gb = b0 + bl, gm = m0 + mi2;
  float cx = c0[(long)gb*MM + gm];
  float cy = c0[(long)gb*MM + gm + 1];

  // prefetch t=0 xp/q
  unsigned short xv[5][2]; float qx, qy;
  #pragma unroll
  for (int j = 0; j < 5; ++j){
    xv[j][0] = XP[((long)0*GG + j*MM + gm    )*BB + gb];
    xv[j][1] = XP[((long)0*GG + j*MM + gm + 1)*BB + gb];
  }
  qx = q[((long)0*BB + gb)*MM + gm];
  qy = q[((long)0*BB + gb)*MM + gm + 1];

  for (int t = 0; t < TT; ++t){
    const unsigned short* hc = (t & 1) ? hb1 : hb0;
    unsigned short*       hn = (t & 1) ? hb0 : hb1;

    // issue h fragment loads straight to regs, kf-major (oldest = kf0 pair)
    bf16x8 af[2][4];
    #pragma unroll
    for (int kf = 0; kf < 4; ++kf)
      #pragma unroll
      for (int rt = 0; rt < 2; ++rt)
        af[rt][kf] = load_coh16b(hc + (long)(b0 + rt*16 + lrow)*MM + w*128 + kf*32 + lhi*8);

    // MFMA with counted waits; SB brackets stop MFMA hoisting past waits (rule 18)
    f32x4 acc[5][2] = {};
    #pragma unroll
    for (int kf = 0; kf < 4; ++kf){
      __builtin_amdgcn_sched_barrier(0);
      if      (kf == 0) asm volatile("s_waitcnt vmcnt(6)" ::: "memory");
      else if (kf == 1) asm volatile("s_waitcnt vmcnt(4)" ::: "memory");
      else if (kf == 2) asm volatile("s_waitcnt vmcnt(2)" ::: "memory");
      else              asm volatile("s_waitcnt vmcnt(0)" ::: "memory");
      __builtin_amdgcn_sched_barrier(0);
      #pragma unroll
      for (int rt = 0; rt < 2; ++rt)
        #pragma unroll
        for (int g = 0; g < 5; ++g)
          acc[g][rt] = __builtin_amdgcn_mfma_f32_16x16x32_bf16(af[rt][kf], Breg[g][kf], acc[g][rt], 0, 0, 0);
    }

    // publish k-partials (D: col=m=lrow, row=b=lhi*4+j -> [m][b] contiguous x4)
    #pragma unroll
    for (int g = 0; g < 5; ++g)
      #pragma unroll
      for (int rt = 0; rt < 2; ++rt)
        *reinterpret_cast<f32x4*>(&Part[w][g][rt][lrow][lhi*4]) = acc[g][rt];
    __syncthreads();                               // syncA: Part ready

    // k-reduction + gates for this thread's 2 states
    float gv[5][2];
    #pragma unroll
    for (int g = 0; g < 5; ++g)
      #pragma unroll
      for (int x = 0; x < 2; ++x)
        gv[g][x] = Part[0][g][rt2][mi2+x][brow] + Part[1][g][rt2][mi2+x][brow]
                 + Part[2][g][rt2][mi2+x][brow] + Part[3][g][rt2][mi2+x][brow]
                 + bf2f(xv[g][x]);
    const float qx_t = qx, qy_t = qy;

    // prefetch next step's xp/q (independent of barrier)
    if (t < TT - 1){
      #pragma unroll
      for (int j = 0; j < 5; ++j){
        xv[j][0] = XP[((long)(t+1)*GG + j*MM + gm    )*BB + gb];
        xv[j][1] = XP[((long)(t+1)*GG + j*MM + gm + 1)*BB + gb];
      }
      qx = q[((long)(t+1)*BB + gb)*MM + gm];
      qy = q[((long)(t+1)*BB + gb)*MM + gm + 1];
    }

    float hx, hy;
    {
      const float i_ = sigmoidf_(gv[0][0]);
      const float fd = sigmoidf_(gv[1][0]);
      const float fl = sigmoidf_(gv[2][0]);
      const float o_ = sigmoidf_(gv[3][0]);
      const float u_ = tanhf_(gv[4][0]);
      const float cn = i_*u_ + fd*qx_t + fl*cx;
      cx = cn; hx = o_*tanhf_(cn);
    }
    {
      const float i_ = sigmoidf_(gv[0][1]);
      const float fd = sigmoidf_(gv[1][1]);
      const float fl = sigmoidf_(gv[2][1]);
      const float o_ = sigmoidf_(gv[3][1]);
      const float u_ = tanhf_(gv[4][1]);
      const float cn = i_*u_ + fd*qy_t + fl*cy;
      cy = cn; hy = o_*tanhf_(cn);
    }
    const unsigned hv = (unsigned)f2bf(hx) | ((unsigned)f2bf(hy) << 16);
    store_coh4(hn + (long)gb*MM + gm, hv);
    if (t == TT - 1){
      out[(long)gb*1024 + gm]           = hx;
      out[(long)gb*1024 + gm + 1]       = hy;
      out[(long)gb*1024 + 512 + gm]     = cx;
      out[(long)gb*1024 + 512 + gm + 1] = cy;
    }

    // per-bt barrier: syncB drains all threads' h stores (vmcnt0 before
    // s_barrier) -> visible at MALL; tid0 arrives + polls; syncC broadcasts.
    if (t != TT - 1){
      __syncthreads();                             // syncB
      if (tid == 0){
        __hip_atomic_fetch_add(cnt, 1u, __ATOMIC_RELAXED, __HIP_MEMORY_SCOPE_AGENT);
        const unsigned target = (unsigned)(t + 1) * 32u;
        unsigned spins = 0;
        while (__hip_atomic_load(cnt, __ATOMIC_RELAXED, __HIP_MEMORY_SCOPE_AGENT) < target){
          __builtin_amdgcn_s_sleep(1);
          if (++spins > (1u << 20)) break;         // safety valve
        }
      }
      __syncthreads();                             // syncC: release all waves
    }
  }
}

extern "C" void kernel_launch(void* const* d_in, const int* in_sizes, int n_in,
                              void* d_out, int out_size, void* d_ws, size_t ws_size,
                              hipStream_t stream){
  (void)in_sizes; (void)n_in; (void)out_size; (void)ws_size;
  const float* word = (const float*)d_in[0];
  const float* tag  = (const float*)d_in[1];
  const float* rel  = (const float*)d_in[2];
  const float* kin  = (const float*)d_in[3];
  const float* q    = (const float*)d_in[4];
  const float* h0   = (const float*)d_in[5];
  const float* c0   = (const float*)d_in[6];
  const float* Ww   = (const float*)d_in[7];
  const float* Wt   = (const float*)d_in[8];
  const float* Wr   = (const float*)d_in[9];
  const float* Wk   = (const float*)d_in[10];
  const float* Wh   = (const float*)d_in[11];
  const float* bias = (const float*)d_in[12];
  float* out = (float*)d_out;

  char* ws = (char*)d_ws;
  size_t off = 0;
  auto alloc = [&](size_t bytes)->void*{
    void* p = ws + off; off = (off + bytes + 255) & ~(size_t)255; return p;
  };
  unsigned short* Abf = (unsigned short*)alloc((size_t)TT*BB*K1P*2);   // 62.9 MB
  unsigned short* WT  = (unsigned short*)alloc((size_t)GG*K1P*2);      // 4.9 MB
  unsigned short* WhT = (unsigned short*)alloc((size_t)GG*MM*2);       // 2.6 MB
  unsigned short* XP  = (unsigned short*)alloc((size_t)TT*BB*GG*2);    // 167.8 MB
  unsigned short* hb0 = (unsigned short*)alloc((size_t)BB*MM*2);
  unsigned short* hb1 = (unsigned short*)alloc((size_t)BB*MM*2);
  unsigned*       cnt = (unsigned*)alloc(8 * 64 * sizeof(unsigned));   // per-bt counters

  hipMemsetAsync(cnt, 0, 8 * 64 * sizeof(unsigned), stream);

  stage_a  <<<dim3((TT*BB*(K1P/8) + 255)/256), 256, 0, stream>>>(word, tag, rel, kin, Abf);
  stage_wt <<<dim3((GG*K1P + 255)/256),        256, 0, stream>>>(Ww, Wt, Wr, Wk, WT);
  stage_wht<<<dim3((GG*MM + 255)/256),         256, 0, stream>>>(Wh, WhT);
  init_h   <<<dim3((BB*MM + 255)/256),         256, 0, stream>>>(h0, hb0);

  gemm_xp<<<dim3(TT*BB/128, GG/128), 256, 0, stream>>>(Abf, WT, bias, XP);

  lstm_fused<<<dim3(256), 256, 0, stream>>>(XP, q, WhT, c0, hb0, hb1, out, cnt);
}